// Round 4
// baseline (211.446 us; speedup 1.0000x reference)
//
#include <hip/hip_runtime.h>
#include <stdint.h>

#define B_ 2
#define S_ 2048
#define D_ 1024
#define H_ 16
#define HD_ 64
#define M_ (B_*S_)   // 4096

typedef __bf16 bf16;
typedef __attribute__((ext_vector_type(8))) __bf16 bf16x8;
typedef __attribute__((ext_vector_type(4))) float f32x4;

// async global->LDS, 16B per lane. LDS dest = uniform base + lane*16.
__device__ __forceinline__ void gload16(const bf16* g, bf16* l) {
    __builtin_amdgcn_global_load_lds(
        (const __attribute__((address_space(1))) void*)g,
        (__attribute__((address_space(3))) void*)l, 16, 0, 0);
}

// ---------------- fp32 -> bf16 converts (single launch) ----------------
__global__ void k_cvt_all(const float* __restrict__ hs,
                          const float* __restrict__ Wq, const float* __restrict__ Wk,
                          const float* __restrict__ Wv, const float* __restrict__ Wo,
                          bf16* __restrict__ hb,
                          bf16* __restrict__ wqb, bf16* __restrict__ wkb,
                          bf16* __restrict__ wvb, bf16* __restrict__ wob) {
    int blk = blockIdx.x;
    const float* s; bf16* d; int base;
    if (blk < 2048) { s = hs; d = hb; base = blk; }
    else {
        int r = blk - 2048; int which = r >> 9; base = r & 511;
        s = (which==0)?Wq:(which==1)?Wk:(which==2)?Wv:Wo;
        d = (which==0)?wqb:(which==1)?wkb:(which==2)?wvb:wob;
    }
    int idx = base*2048 + threadIdx.x*8;
    float4 a = *(const float4*)(s + idx);
    float4 b = *(const float4*)(s + idx + 4);
    bf16 o[8] = {(bf16)a.x,(bf16)a.y,(bf16)a.z,(bf16)a.w,
                 (bf16)b.x,(bf16)b.y,(bf16)b.z,(bf16)b.w};
    *(int4*)(d + idx) = *(const int4*)o;
}

// ---------------- QKV projection GEMM (coalesced LDS-transpose epilogue) ----
// z=0: Q -> [BH][S][HD] scaled 1/8 ; z=1: K -> [BH][S][HD] ; z=2: V -> [BH][HD][S]
__global__ __launch_bounds__(256) void k_gemm_qkv(
    const bf16* __restrict__ X,
    const bf16* __restrict__ Wq, const bf16* __restrict__ Wk, const bf16* __restrict__ Wv,
    const float* __restrict__ bq, const float* __restrict__ bk, const float* __restrict__ bv,
    bf16* __restrict__ Qo, bf16* __restrict__ Ko, bf16* __restrict__ Vo)
{
    const int z = blockIdx.z;
    const bf16* W = (z==0) ? Wq : (z==1) ? Wk : Wv;
    const float* bias = (z==0) ? bq : (z==1) ? bk : bv;
    const int n0 = blockIdx.x * 128;
    const int m0 = blockIdx.y * 128;
    const int t = threadIdx.x;
    const int w = t >> 6, lane = t & 63, quad = lane >> 4, l15 = lane & 15;
    const int lr = lane >> 3;
    const int lc = (lane & 7) ^ lr;
    const int sx = l15 & 7;
    const int mw = (w >> 1) * 64, nw = (w & 1) * 64;

    __shared__ __align__(16) char smraw[128*136*2];  // 34816 B, aliased
    bf16* As  = (bf16*)smraw;               // [128][64]
    bf16* Bs  = (bf16*)(smraw + 16384);     // [128][64]
    bf16* epi = (bf16*)smraw;               // [128][136]

    f32x4 acc[4][4];
    #pragma unroll
    for (int i = 0; i < 4; i++)
        #pragma unroll
        for (int j = 0; j < 4; j++)
            acc[i][j] = (f32x4){0.f,0.f,0.f,0.f};

    const bf16* gA = X + (size_t)(m0 + w*8 + lr)*D_ + lc*8;
    const bf16* gB = W + (size_t)(n0 + w*8 + lr)*D_ + lc*8;

    for (int k0 = 0; k0 < D_; k0 += 64) {
        #pragma unroll
        for (int c = 0; c < 4; c++) {
            gload16(gA + (size_t)c*32*D_ + k0, &As[c*2048 + w*512]);
            gload16(gB + (size_t)c*32*D_ + k0, &Bs[c*2048 + w*512]);
        }
        __syncthreads();
        #pragma unroll
        for (int ks = 0; ks < 2; ks++) {
            bf16x8 af[4], bfr[4];
            #pragma unroll
            for (int i = 0; i < 4; i++)
                af[i] = *(const bf16x8*)&As[(mw + i*16 + l15)*64 + (((ks*4+quad)^sx)*8)];
            #pragma unroll
            for (int j = 0; j < 4; j++)
                bfr[j] = *(const bf16x8*)&Bs[(nw + j*16 + l15)*64 + (((ks*4+quad)^sx)*8)];
            #pragma unroll
            for (int i = 0; i < 4; i++)
                #pragma unroll
                for (int j = 0; j < 4; j++)
                    acc[i][j] = __builtin_amdgcn_mfma_f32_16x16x32_bf16(af[i], bfr[j], acc[i][j], 0, 0, 0);
        }
        __syncthreads();
    }

    // ---- epilogue: acc -> LDS (transposed layouts) -> coalesced global ----
    const float scale = (z == 0) ? 0.125f : 1.0f;
    if (z == 2) {
        #pragma unroll
        for (int j = 0; j < 4; j++) {
            int n = nw + j*16 + l15;
            float bn = bias[n0 + n];
            #pragma unroll
            for (int i = 0; i < 4; i++) {
                int mloc = mw + i*16 + quad*4;
                union { bf16 h4[4]; uint2 u; } pk;
                #pragma unroll
                for (int r = 0; r < 4; r++) pk.h4[r] = (bf16)(acc[i][j][r] + bn);
                *(uint2*)&epi[n*136 + mloc] = pk.u;
            }
        }
    } else {
        #pragma unroll
        for (int j = 0; j < 4; j++) {
            int n = nw + j*16 + l15;
            float bn = bias[n0 + n];
            #pragma unroll
            for (int i = 0; i < 4; i++) {
                int mloc = mw + i*16 + quad*4;
                #pragma unroll
                for (int r = 0; r < 4; r++)
                    epi[(mloc + r)*136 + n] = (bf16)((acc[i][j][r] + bn) * scale);
            }
        }
    }
    __syncthreads();
    if (z == 2) {
        #pragma unroll
        for (int kk = 0; kk < 8; kk++) {
            int c = t + 256*kk;
            int row = c >> 4;             // local n (dim)
            int mcol = (c & 15) * 8;      // local m (token)
            int4 val = *(const int4*)&epi[row*136 + mcol];
            int n = n0 + row; int hh = n >> 6, hd = n & 63;
            int m = m0 + mcol; int bb = m >> 11, s = m & 2047;
            *(int4*)&Vo[((size_t)((bb*H_ + hh)*HD_ + hd))*S_ + s] = val;
        }
    } else {
        bf16* Out = (z == 0) ? Qo : Ko;
        #pragma unroll
        for (int kk = 0; kk < 8; kk++) {
            int c = t + 256*kk;
            int row = c >> 4;             // local m (token)
            int ncol = (c & 15) * 8;      // local n (dim)
            int4 val = *(const int4*)&epi[row*136 + ncol];
            int m = m0 + row; int bb = m >> 11, s = m & 2047;
            int n = n0 + ncol; int hh = n >> 6, hd = n & 63;
            *(int4*)&Out[((size_t)((bb*H_ + hh)*S_ + s))*HD_ + hd] = val;
        }
    }
}

// ---------------- output projection GEMM (64x128 tile) ----------------
__global__ __launch_bounds__(256) void k_gemm_out(
    const bf16* __restrict__ X, const bf16* __restrict__ W,
    const float* __restrict__ bias, float* __restrict__ Out)
{
    const int n0 = blockIdx.x * 128;
    const int m0 = blockIdx.y * 64;
    const int t = threadIdx.x;
    const int w = t >> 6, lane = t & 63, quad = lane >> 4, l15 = lane & 15;
    const int lr = lane >> 3;
    const int lc = (lane & 7) ^ lr;
    const int sx = l15 & 7;
    const int nw = w * 32;

    __shared__ __align__(16) bf16 As[64*64];
    __shared__ __align__(16) bf16 Bs[128*64];

    f32x4 acc[4][2];
    #pragma unroll
    for (int i = 0; i < 4; i++)
        #pragma unroll
        for (int j = 0; j < 2; j++)
            acc[i][j] = (f32x4){0.f,0.f,0.f,0.f};

    const bf16* gA = X + (size_t)(m0 + w*8 + lr)*D_ + lc*8;
    const bf16* gB = W + (size_t)(n0 + w*8 + lr)*D_ + lc*8;

    for (int k0 = 0; k0 < D_; k0 += 64) {
        #pragma unroll
        for (int c = 0; c < 2; c++)
            gload16(gA + (size_t)c*32*D_ + k0, &As[c*2048 + w*512]);
        #pragma unroll
        for (int c = 0; c < 4; c++)
            gload16(gB + (size_t)c*32*D_ + k0, &Bs[c*2048 + w*512]);
        __syncthreads();
        #pragma unroll
        for (int ks = 0; ks < 2; ks++) {
            bf16x8 af[4], bfr[2];
            #pragma unroll
            for (int i = 0; i < 4; i++)
                af[i] = *(const bf16x8*)&As[(i*16 + l15)*64 + (((ks*4+quad)^sx)*8)];
            #pragma unroll
            for (int j = 0; j < 2; j++)
                bfr[j] = *(const bf16x8*)&Bs[(nw + j*16 + l15)*64 + (((ks*4+quad)^sx)*8)];
            #pragma unroll
            for (int i = 0; i < 4; i++)
                #pragma unroll
                for (int j = 0; j < 2; j++)
                    acc[i][j] = __builtin_amdgcn_mfma_f32_16x16x32_bf16(af[i], bfr[j], acc[i][j], 0, 0, 0);
        }
        __syncthreads();
    }

    #pragma unroll
    for (int j = 0; j < 2; j++) {
        int n = n0 + nw + j*16 + l15;
        float bn = bias[n];
        #pragma unroll
        for (int i = 0; i < 4; i++) {
            int mbase = m0 + i*16 + quad*4;
            #pragma unroll
            for (int r = 0; r < 4; r++)
                Out[(size_t)(mbase + r)*D_ + n] = acc[i][j][r] + bn;
        }
    }
}

// ---------------- fused attention v4: single-barrier pipelined K-loop ----------------
// Q-tile 128/block (512 blocks). QK^T k-split across waves (Q in regs), PV q-split.
// K dbuf, V tbuf, P dbuf -> ONE __syncthreads per iter; DMA issued at loop top.
__global__ __launch_bounds__(256, 2) void k_attn(
    const bf16* __restrict__ Q, const bf16* __restrict__ K, const bf16* __restrict__ Vt,
    const float* __restrict__ mask, bf16* __restrict__ Ctx)
{
    const int bh = blockIdx.y;
    const int b = bh >> 4, h = bh & 15;
    const int q0 = blockIdx.x * 128;
    const int t = threadIdx.x;
    const int w = t >> 6, lane = t & 63, quad = lane >> 4, l15 = lane & 15;
    const int lr = lane >> 3;
    const int lc = (lane & 7) ^ lr;
    const int sx = l15 & 7;

    __shared__ __align__(16) bf16 Ks[2][64*64];   // 16 KB
    __shared__ __align__(16) bf16 Vs[3][64*64];   // 24 KB
    __shared__ __align__(16) bf16 Ps[2][128*64];  // 32 KB
    __shared__ float lsumP[4][128];

    // Q fragments in registers: all 128 q rows (B-operand), 16 frags
    bf16x8 qf[8][2];
    const bf16* Qbase = Q + ((size_t)bh*S_ + q0)*HD_;
    #pragma unroll
    for (int qs = 0; qs < 8; qs++)
        #pragma unroll
        for (int ks = 0; ks < 2; ks++)
            qf[qs][ks] = *(const bf16x8*)&Qbase[(size_t)(qs*16 + l15)*HD_ + ks*32 + quad*8];

    f32x4 cacc[2][4];
    #pragma unroll
    for (int i = 0; i < 2; i++)
        #pragma unroll
        for (int j = 0; j < 4; j++)
            cacc[i][j] = (f32x4){0.f,0.f,0.f,0.f};
    float lac[8];
    #pragma unroll
    for (int qs = 0; qs < 8; qs++) lac[qs] = 0.f;

    const bf16* Kst = K + ((size_t)bh*S_ + w*8 + lr)*HD_ + lc*8;
    const bf16* Vst = Vt + ((size_t)bh*HD_ + w*8 + lr)*S_ + lc*8;

    // prologue: stage tile 0
    #pragma unroll
    for (int c = 0; c < 2; c++)
        gload16(Kst + (size_t)c*32*HD_, &Ks[0][c*2048 + w*512]);
    #pragma unroll
    for (int c = 0; c < 2; c++)
        gload16(Vst + (size_t)c*32*S_, &Vs[0][c*2048 + w*512]);
    __syncthreads();

    int vb = 0;
    for (int it = 0; it < S_/64; it++) {
        const int kb = it & 1;
        const int pb = it & 1;
        const int k0 = it*64;
        const int vn = (vb == 2) ? 0 : vb + 1;

        // prefetch tile it+1 at loop TOP (drained by this iter's barrier;
        // QK+sigmoid covers the latency)
        if (it < S_/64 - 1) {
            const int k1 = k0 + 64;
            #pragma unroll
            for (int c = 0; c < 2; c++)
                gload16(Kst + (size_t)(k1 + c*32)*HD_, &Ks[kb^1][c*2048 + w*512]);
            #pragma unroll
            for (int c = 0; c < 2; c++)
                gload16(Vst + (size_t)c*32*S_ + k1, &Vs[vn][c*2048 + w*512]);
        }

        float4 m4 = *(const float4*)&mask[(size_t)b*S_ + k0 + w*16 + quad*4];
        float mv[4] = {(1.0f-m4.x)*-10000.0f, (1.0f-m4.y)*-10000.0f,
                       (1.0f-m4.z)*-10000.0f, (1.0f-m4.w)*-10000.0f};

        // QK: S^T rows k in [w*16, w*16+16), all 128 q
        f32x4 st[8];
        #pragma unroll
        for (int qs = 0; qs < 8; qs++) st[qs] = (f32x4){0.f,0.f,0.f,0.f};
        #pragma unroll
        for (int ks = 0; ks < 2; ks++) {
            bf16x8 af = *(const bf16x8*)&Ks[kb][(w*16 + l15)*64 + (((ks*4+quad)^sx)*8)];
            #pragma unroll
            for (int qs = 0; qs < 8; qs++)
                st[qs] = __builtin_amdgcn_mfma_f32_16x16x32_bf16(af, qf[qs][ks], st[qs], 0, 0, 0);
        }

        // mask + polynomial sigmoid + P write into Ps[pb]
        const int c8 = (w*2 + (quad>>1)) ^ sx;
        #pragma unroll
        for (int qs = 0; qs < 8; qs++) {
            union { bf16 h4[4]; uint2 u; } pk;
            #pragma unroll
            for (int r = 0; r < 4; r++) {
                float s = st[qs][r] + mv[r];
                float c = __builtin_amdgcn_fmed3f(s, -3.0f, 3.0f);
                float u = fmaf(c*c, -0.01f, 0.25f);
                float sg = fmaf(c, u, 0.5f);
                sg = __builtin_amdgcn_fmed3f(sg, 0.01f, 0.99f);
                lac[qs] += sg;
                pk.h4[r] = (bf16)sg;
            }
            *(uint2*)&Ps[pb][(qs*16 + l15)*64 + c8*8 + (quad&1)*4] = pk.u;
        }
        __syncthreads();   // the ONLY barrier: P visible, DMA drained

        // PV: wave owns q in [w*32, w*32+32); reads Ps[pb], Vs[vb]
        #pragma unroll
        for (int ks = 0; ks < 2; ks++) {
            bf16x8 pf[2], vf[4];
            #pragma unroll
            for (int m2 = 0; m2 < 2; m2++)
                pf[m2] = *(const bf16x8*)&Ps[pb][(w*32 + m2*16 + l15)*64 + (((ks*4+quad)^sx)*8)];
            #pragma unroll
            for (int nt = 0; nt < 4; nt++)
                vf[nt] = *(const bf16x8*)&Vs[vb][(nt*16 + l15)*64 + (((ks*4+quad)^sx)*8)];
            #pragma unroll
            for (int m2 = 0; m2 < 2; m2++)
                #pragma unroll
                for (int nt = 0; nt < 4; nt++)
                    cacc[m2][nt] = __builtin_amdgcn_mfma_f32_16x16x32_bf16(pf[m2], vf[nt], cacc[m2][nt], 0, 0, 0);
        }
        vb = vn;
        // no trailing barrier: next iter's P writes go to the other P buffer,
        // next DMA targets buffers no live reader can touch (K dbuf / V tbuf proof)
    }

    // cross-wave row-sum reduce
    #pragma unroll
    for (int qs = 0; qs < 8; qs++) {
        float v = lac[qs];
        v += __shfl_xor(v, 16);
        v += __shfl_xor(v, 32);
        if (quad == 0) lsumP[w][qs*16 + l15] = v;
    }
    __syncthreads();

    // normalize + store ctx
    #pragma unroll
    for (int m2 = 0; m2 < 2; m2++) {
        #pragma unroll
        for (int r = 0; r < 4; r++) {
            int q = w*32 + m2*16 + quad*4 + r;
            float s = lsumP[0][q] + lsumP[1][q] + lsumP[2][q] + lsumP[3][q];
            float rinv = 1.0f / (s + 1e-8f);
            size_t row = (size_t)(b*S_ + q0 + q);
            #pragma unroll
            for (int nt = 0; nt < 4; nt++)
                Ctx[row*D_ + h*HD_ + nt*16 + l15] = (bf16)(cacc[m2][nt][r] * rinv);
        }
    }
}

extern "C" void kernel_launch(void* const* d_in, const int* in_sizes, int n_in,
                              void* d_out, int out_size, void* d_ws, size_t ws_size,
                              hipStream_t stream) {
    const float* hs   = (const float*)d_in[0];
    const float* mask = (const float*)d_in[1];
    const float* Wq   = (const float*)d_in[2];
    const float* bq   = (const float*)d_in[3];
    const float* Wk   = (const float*)d_in[4];
    const float* bk   = (const float*)d_in[5];
    const float* Wv   = (const float*)d_in[6];
    const float* bv   = (const float*)d_in[7];
    const float* Wo   = (const float*)d_in[8];
    const float* bo   = (const float*)d_in[9];
    float* out = (float*)d_out;

    char* ws = (char*)d_ws;
    const size_t MB = 1024*1024;
    bf16* hb   = (bf16*)(ws);            // [M_,D_]        8 MB
    bf16* wqb  = (bf16*)(ws + 8*MB);     // [D_,D_]        2 MB
    bf16* wkb  = (bf16*)(ws + 10*MB);
    bf16* wvb  = (bf16*)(ws + 12*MB);
    bf16* wob  = (bf16*)(ws + 14*MB);
    bf16* qb   = (bf16*)(ws + 16*MB);    // [BH][S][HD]    8 MB
    bf16* kb   = (bf16*)(ws + 24*MB);    // [BH][S][HD]    8 MB
    bf16* vtb  = (bf16*)(ws + 32*MB);    // [BH][HD][S]    8 MB
    bf16* ctxb = (bf16*)(ws + 40*MB);    // [M_,D_]        8 MB

    k_cvt_all<<<2048 + 4*512, 256, 0, stream>>>(hs, Wq, Wk, Wv, Wo, hb, wqb, wkb, wvb, wob);

    k_gemm_qkv<<<dim3(D_/128, M_/128, 3), 256, 0, stream>>>(
        hb, wqb, wkb, wvb, bq, bk, bv, qb, kb, vtb);

    k_attn<<<dim3(S_/128, B_*H_), 256, 0, stream>>>(qb, kb, vtb, mask, ctxb);

    k_gemm_out<<<dim3(D_/128, M_/64), 256, 0, stream>>>(ctxb, wob, bo, out);
}